// Round 17
// baseline (140.021 us; speedup 1.0000x reference)
//
#include <hip/hip_runtime.h>
#include <hip/hip_bf16.h>
#include <stdint.h>

typedef int i32x4 __attribute__((ext_vector_type(4)));
typedef int i32x8 __attribute__((ext_vector_type(8)));
typedef float f32x4 __attribute__((ext_vector_type(4)));

// ---------------------------------------------------------------------------
// Pass 1 (x2): binarize f32 -> i8 sign (+1 / -1 / 0). VERBATIM round-6 code:
// the only binarize configuration ever measured at HBM-class rate
// (pair ~40.6 us = 6.2 TB/s vs every fp4-pack variant at ~3 TB/s).
// ---------------------------------------------------------------------------
__device__ __forceinline__ signed char sign_i8(float x) {
  return x > 0.0f ? (signed char)1 : (x < 0.0f ? (signed char)-1 : (signed char)0);
}

__global__ void binarize_i8(const float* __restrict__ in,
                            signed char* __restrict__ out,
                            int n8) {
  int idx = blockIdx.x * blockDim.x + threadIdx.x;
  int stride = gridDim.x * blockDim.x;
  const float4* in4 = (const float4*)in;
  uint2* out2 = (uint2*)out;
  for (int i = idx; i < n8; i += stride) {
    float4 a = in4[2 * i];
    float4 b = in4[2 * i + 1];
    union { signed char c[8]; uint2 u; } p;
    p.c[0] = sign_i8(a.x); p.c[1] = sign_i8(a.y);
    p.c[2] = sign_i8(a.z); p.c[3] = sign_i8(a.w);
    p.c[4] = sign_i8(b.x); p.c[5] = sign_i8(b.y);
    p.c[6] = sign_i8(b.z); p.c[7] = sign_i8(b.w);
    out2[i] = p.u;
  }
}

// ---------------------------------------------------------------------------
// Pass 2: repack i8 signs -> fp4 e2m1 nibbles (0x01->0x2, 0xFF->0xA, 0->0x0),
// low nibble = lower k. Pure streaming: reads the contiguous 50.3 MB i8
// region (L2/L3-hot, just written), writes 25.2 MB. 16 i8 -> uint2 per
// thread-iter, 2048x256 grid-stride (6 iters exactly). Branch-free:
//   nz  = (((u & 0x7f7f7f7f) + 0x7f7f7f7f) | u) & 0x80808080  (byte != 0)
//   nib = (nz >> 6) | ((u & 0x80808080) >> 4)    // 0x02 | 0x08-if-negative
//   pair-compress: r = (nib | (nib>>4)) & 0x00FF00FF; p16 = (r|(r>>8)) & 0xFFFF
// ---------------------------------------------------------------------------
__device__ __forceinline__ unsigned int nib4(unsigned int u) {
  unsigned int nz = (((u & 0x7f7f7f7fu) + 0x7f7f7f7fu) | u) & 0x80808080u;
  return (nz >> 6) | ((u & 0x80808080u) >> 4);
}
__device__ __forceinline__ unsigned int p16(unsigned int u) {
  unsigned int n = nib4(u);
  unsigned int r = (n | (n >> 4)) & 0x00FF00FFu;
  return (r | (r >> 8)) & 0xFFFFu;
}

__global__ void repack_i8_fp4(const uint4* __restrict__ in,
                              uint2* __restrict__ out,
                              int n16) {
  int idx = blockIdx.x * blockDim.x + threadIdx.x;
  int stride = gridDim.x * blockDim.x;
  for (int i = idx; i < n16; i += stride) {
    uint4 v = in[i];
    uint2 o;
    o.x = p16(v.x) | (p16(v.y) << 16);
    o.y = p16(v.z) | (p16(v.w) << 16);
    out[i] = o;
  }
}

// ---------------------------------------------------------------------------
// Pass 3: C = A * B^T, fp4 +-1/0 inputs, MX-scaled MFMA (scale=1.0), f32 out.
// EXACT: products are +-1/0, f32 accumulation of <=4096 integers is exact.
// UNCHANGED since round 12 (steady-state ~43 us ~= 88% of the fp4 16x16
// MFMA ubench ceiling; conflicts 0 -- at its structural roofline).
// ---------------------------------------------------------------------------
__device__ __forceinline__ void load_lds16(const void* g, void* l) {
  __builtin_amdgcn_global_load_lds(
      (const __attribute__((address_space(1))) void*)g,
      (__attribute__((address_space(3))) void*)l,
      16, 0, 0);
}

__device__ __forceinline__ void bar() {
  asm volatile("s_barrier" ::: "memory");
}
template <int N>
__device__ __forceinline__ void waitvm() {
  asm volatile("s_waitcnt vmcnt(%0)" ::"i"(N) : "memory");
}

__device__ __forceinline__ i32x8 rd8(const char* p) {
  i32x4 q = *(const i32x4*)p;
  return __builtin_shufflevector(q, q, 0, 1, 2, 3, -1, -1, -1, -1);
}

__global__ __launch_bounds__(512, 2)
void gemm_bt_fp4(const unsigned char* __restrict__ A,
                 const unsigned char* __restrict__ B,
                 float* __restrict__ C,
                 int M, int N, int K, int nbn) {
  constexpr int BM = 256, BN = 256;
  __shared__ __attribute__((aligned(16))) char lds[4 * 32768];

  // XCD-aware bijective swizzle (grid = 32*16 = 512, multiple of 8)
  int nwg = gridDim.x;
  int bid = blockIdx.x;
  int cpx = nwg >> 3;
  int swz = (bid & 7) * cpx + (bid >> 3);
  int tm = swz / nbn;
  int tn = swz % nbn;

  const int t = threadIdx.x;
  const int lane = t & 63;
  const int wid = t >> 6;       // 0..7
  const int wm = wid >> 2;      // 0..1  (wave row: 128 rows)
  const int wn = wid & 3;       // 0..3  (wave col: 64 cols)
  const int lrow = lane & 15;
  const int kg = lane >> 4;     // 0..3 (32 contiguous fp4 k-elems = 16 B)

  const int Kb = K >> 1;        // row stride in bytes (fp4 packed)
  const size_t rowA0 = (size_t)tm * BM;
  const size_t rowB0 = (size_t)tn * BN;

  f32x4 acc[8][4] = {};

  const int nt = K / 128;  // 32

  // --- staging lane constants (inverse-swizzled global source) ---
  const int soff0 = wid * 1024 + lane * 16;
  const int srow0 = soff0 >> 6;
  const int scb0 = ((soff0 >> 4) & 3) ^ ((srow0 >> 1) & 3);
  const int soff1 = 8192 + wid * 1024 + lane * 16;
  const int srow1 = soff1 >> 6;
  const int scb1 = ((soff1 >> 4) & 3) ^ ((srow1 >> 1) & 3);

  auto stage = [&](int tt) {
    const int b = tt & 3;
    const int k0b = tt * 64;    // tile K-offset in BYTES (128 fp4 = 64 B)
    load_lds16(A + (rowA0 + srow0) * Kb + k0b + scb0 * 16,
               lds + b * 32768 + wid * 1024);
    load_lds16(A + (rowA0 + srow1) * Kb + k0b + scb1 * 16,
               lds + b * 32768 + 8192 + wid * 1024);
    load_lds16(B + (rowB0 + srow0) * Kb + k0b + scb0 * 16,
               lds + b * 32768 + 16384 + wid * 1024);
    load_lds16(B + (rowB0 + srow1) * Kb + k0b + scb1 * 16,
               lds + b * 32768 + 16384 + 8192 + wid * 1024);
  };

  // --- swizzled read column (byte) within a 64B LDS row (proven 0-conflict)
  const int rcol = ((kg ^ ((lrow >> 1) & 3)) << 4);
  const int aoff = (wm * 128 + lrow) * 64 + rcol;
  const int boff = 16384 + (wn * 64 + lrow) * 64 + rcol;

  const int SC = 0x7F7F7F7F;  // E8M0 scale bytes: 127 -> 2^0

  // prologue: stage tiles 0 and 1 (8 loads outstanding per thread)
  stage(0); stage(1);

  for (int tt = 0; tt < nt; ++tt) {
    const int b = tt & 3;
    if (tt + 1 < nt) waitvm<4>(); else waitvm<0>();
    bar();  // the only barrier per tile

    const char* Ab = lds + b * 32768 + aoff;
    const char* Bb = lds + b * 32768 + boff;

    // half-phase 1: B frags + A frags 0..3, restage, 16 MFMAs
    i32x8 bf[4], af[4];
    #pragma unroll
    for (int n = 0; n < 4; ++n)
      bf[n] = rd8(Bb + n * 1024);
    #pragma unroll
    for (int m = 0; m < 4; ++m)
      af[m] = rd8(Ab + m * 1024);

    if (tt + 2 < nt) stage(tt + 2);

    #pragma unroll
    for (int m = 0; m < 4; ++m)
      #pragma unroll
      for (int n = 0; n < 4; ++n)
        acc[m][n] = __builtin_amdgcn_mfma_scale_f32_16x16x128_f8f6f4(
            af[m], bf[n], acc[m][n], 4, 4, 0, SC, 0, SC);

    // half-phase 2: A frags 4..7, 16 MFMAs
    i32x8 ag[4];
    #pragma unroll
    for (int m = 0; m < 4; ++m)
      ag[m] = rd8(Ab + (m + 4) * 1024);

    #pragma unroll
    for (int m = 0; m < 4; ++m)
      #pragma unroll
      for (int n = 0; n < 4; ++n)
        acc[m + 4][n] = __builtin_amdgcn_mfma_scale_f32_16x16x128_f8f6f4(
            ag[m], bf[n], acc[m + 4][n], 4, 4, 0, SC, 0, SC);
  }

  // --- epilogue: 16x16 C/D layout col = lane&15, row = (lane>>4)*4 + r ---
  const size_t cRow0 = rowA0 + (size_t)wm * 128;
  const size_t cCol0 = rowB0 + (size_t)wn * 64;
  const int orow = kg * 4;
  #pragma unroll
  for (int m = 0; m < 8; ++m)
    #pragma unroll
    for (int n = 0; n < 4; ++n)
      #pragma unroll
      for (int r = 0; r < 4; ++r)
        C[(cRow0 + m * 16 + orow + r) * N + cCol0 + n * 16 + lrow] =
            acc[m][n][r];
}

// ---------------------------------------------------------------------------
extern "C" void kernel_launch(void* const* d_in, const int* in_sizes, int n_in,
                              void* d_out, int out_size, void* d_ws, size_t ws_size,
                              hipStream_t stream) {
  const float* x = (const float*)d_in[0];
  const float* w = (const float*)d_in[1];
  float* out = (float*)d_out;

  const int K = 4096;
  const int M = in_sizes[0] / K;   // 8192
  const int N = in_sizes[1] / K;   // 4096

  // d_ws layout: [xb4 16.8MB][wb4 8.4MB][xb8 33.5MB][wb8 16.8MB] = 75.5MB
  unsigned char* xb4 = (unsigned char*)d_ws;
  unsigned char* wb4 = xb4 + (size_t)M * (K / 2);
  signed char* xb8 = (signed char*)(wb4 + (size_t)N * (K / 2));
  signed char* wb8 = xb8 + (size_t)M * K;   // contiguous after xb8

  // 1+2: verbatim round-6 binarize (proven 6.2 TB/s shape)
  int n8x = (M * K) / 8;
  int n8w = (N * K) / 8;
  binarize_i8<<<dim3(2048), dim3(256), 0, stream>>>(x, xb8, n8x);
  binarize_i8<<<dim3(2048), dim3(256), 0, stream>>>(w, wb8, n8w);

  // 3: repack the contiguous i8 region (x then w) into the fp4 region
  int n16 = (M * K + N * K) / 16;   // 3,145,728 -> exactly 6 iters
  repack_i8_fp4<<<dim3(2048), dim3(256), 0, stream>>>(
      (const uint4*)xb8, (uint2*)xb4, n16);

  // 4: GEMM (unchanged)
  int nbm = M / 256;  // 32
  int nbn = N / 256;  // 16
  gemm_bt_fp4<<<dim3(nbm * nbn), dim3(512), 0, stream>>>(
      xb4, wb4, out, M, N, K, nbn);
}

// Round 18
// 124.877 us; speedup vs baseline: 1.1213x; 1.1213x over previous
//
#include <hip/hip_runtime.h>
#include <hip/hip_bf16.h>
#include <stdint.h>

typedef int i32x4 __attribute__((ext_vector_type(4)));
typedef int i32x8 __attribute__((ext_vector_type(8)));
typedef float f32x16 __attribute__((ext_vector_type(16)));

// ---------------------------------------------------------------------------
// Pass 1: binarize f32 -> fp4 e2m1 sign nibble (+1=0x2, -1=0xA, 0=0x0),
// packed 2 elems/byte, low nibble = lower k. VERBATIM round-14 v3 (best
// measured variant: ~45 us by corrected subtraction; all other shapes 45-55).
// ---------------------------------------------------------------------------
__device__ __forceinline__ unsigned int sign_nib(float x) {
  return x > 0.0f ? 0x2u : (x < 0.0f ? 0xAu : 0x0u);
}

__device__ __forceinline__ unsigned short pack4(const float4& a) {
  return (unsigned short)(sign_nib(a.x)
                        | (sign_nib(a.y) << 4)
                        | (sign_nib(a.z) << 8)
                        | (sign_nib(a.w) << 12));
}

__global__ __launch_bounds__(256)
void binarize_fp4_v3(const float* __restrict__ x,
                     const float* __restrict__ w,
                     unsigned short* __restrict__ xb,
                     unsigned short* __restrict__ wb,
                     int bx) {   // bx = number of blocks covering x
  const float4* src;
  unsigned short* dst;
  int b = blockIdx.x;
  if (b < bx) { src = (const float4*)x; dst = xb; }
  else        { src = (const float4*)w; dst = wb; b -= bx; }

  const size_t base = (size_t)b * 1024 + threadIdx.x;
  float4 v0 = src[base];
  float4 v1 = src[base + 256];
  float4 v2 = src[base + 512];
  float4 v3 = src[base + 768];

  dst[base]       = pack4(v0);
  dst[base + 256] = pack4(v1);
  dst[base + 512] = pack4(v2);
  dst[base + 768] = pack4(v3);
}

// ---------------------------------------------------------------------------
// Pass 2: C = A * B^T, fp4 +-1/0 inputs, MX-scaled MFMA (scale=1.0), f32 out.
// EXACT: products +-1/0; f32 accumulation of <=4096 integers exact; A and B
// fragments use identical packing/geometry so any HW k-ordering cancels.
// Round 18: switch 16x16x128 -> 32x32x64 f8f6f4 (9099 vs 7228 TF ceiling;
// MFMA term 1426 -> 1133 cyc/tile). Staging, XOR swizzle, 4-buffer rotation,
// counted vmcnt, ONE asm barrier per tile, stage(tt+2): ALL byte-identical
// to the proven round-16 flow. Only fragment addressing (12 reads/tile:
// A 4mf x 2ks, B 2nf x 2ks; blk = (2*ks+h) ^ ((row>>1)&3), h = lane>>5),
// 16 MFMAs/tile, and the m74/m101-verified 32x32 C/D epilogue change.
// Bank check: each consecutive-8-lane group of a frag read covers all 32
// banks exactly once (row parity -> +16 bank offset; row>>1 -> block rot).
// ---------------------------------------------------------------------------
__device__ __forceinline__ void load_lds16(const void* g, void* l) {
  __builtin_amdgcn_global_load_lds(
      (const __attribute__((address_space(1))) void*)g,
      (__attribute__((address_space(3))) void*)l,
      16, 0, 0);
}

__device__ __forceinline__ void bar() {
  asm volatile("s_barrier" ::: "memory");
}
template <int N>
__device__ __forceinline__ void waitvm() {
  asm volatile("s_waitcnt vmcnt(%0)" ::"i"(N) : "memory");
}

__device__ __forceinline__ i32x8 rd8(const char* p) {
  i32x4 q = *(const i32x4*)p;
  return __builtin_shufflevector(q, q, 0, 1, 2, 3, -1, -1, -1, -1);
}

__global__ __launch_bounds__(512, 2)
void gemm_bt_fp4(const unsigned char* __restrict__ A,
                 const unsigned char* __restrict__ B,
                 float* __restrict__ C,
                 int M, int N, int K, int nbn) {
  constexpr int BM = 256, BN = 256;
  __shared__ __attribute__((aligned(16))) char lds[4 * 32768];

  // XCD-aware bijective swizzle (grid = 32*16 = 512, multiple of 8)
  int nwg = gridDim.x;
  int bid = blockIdx.x;
  int cpx = nwg >> 3;
  int swz = (bid & 7) * cpx + (bid >> 3);
  int tm = swz / nbn;
  int tn = swz % nbn;

  const int t = threadIdx.x;
  const int lane = t & 63;
  const int wid = t >> 6;       // 0..7
  const int wm = wid >> 2;      // 0..1  (wave row: 128 rows)
  const int wn = wid & 3;       // 0..3  (wave col: 64 cols)
  const int l31 = lane & 31;    // row within 32x32 fragment
  const int h = lane >> 5;      // k-half within one MFMA's K=64

  const int Kb = K >> 1;        // row stride in bytes (fp4 packed)
  const size_t rowA0 = (size_t)tm * BM;
  const size_t rowB0 = (size_t)tn * BN;

  f32x16 acc[4][2] = {};

  const int nt = K / 128;  // 32 (BK = 128 fp4 elems = 64 B/row, 2 ksteps)

  // --- staging lane constants (inverse-swizzled global source; unchanged) ---
  const int soff0 = wid * 1024 + lane * 16;
  const int srow0 = soff0 >> 6;
  const int scb0 = ((soff0 >> 4) & 3) ^ ((srow0 >> 1) & 3);
  const int soff1 = 8192 + wid * 1024 + lane * 16;
  const int srow1 = soff1 >> 6;
  const int scb1 = ((soff1 >> 4) & 3) ^ ((srow1 >> 1) & 3);

  auto stage = [&](int tt) {
    const int b = tt & 3;
    const int k0b = tt * 64;    // tile K-offset in BYTES
    load_lds16(A + (rowA0 + srow0) * Kb + k0b + scb0 * 16,
               lds + b * 32768 + wid * 1024);
    load_lds16(A + (rowA0 + srow1) * Kb + k0b + scb1 * 16,
               lds + b * 32768 + 8192 + wid * 1024);
    load_lds16(B + (rowB0 + srow0) * Kb + k0b + scb0 * 16,
               lds + b * 32768 + 16384 + wid * 1024);
    load_lds16(B + (rowB0 + srow1) * Kb + k0b + scb1 * 16,
               lds + b * 32768 + 16384 + 8192 + wid * 1024);
  };

  // --- swizzled fragment read columns (byte) within a 64B LDS row ---
  // logical block for (ks,h) = 2*ks + h; phys = logical ^ ((row>>1)&3);
  // (row>>1)&3 == (l31>>1)&3 since wm*128, mf*32, wn*64, nf*32 are =0 mod 4.
  const int rp = (l31 >> 1) & 3;
  const int pc0 = ((h ^ rp) << 4);          // kstep 0
  const int pc1 = (((2 + h) ^ rp) << 4);    // kstep 1

  const int SC = 0x7F7F7F7F;  // E8M0 scale bytes: 127 -> 2^0

  // prologue: stage tiles 0 and 1 (8 loads outstanding per thread)
  stage(0); stage(1);

  for (int tt = 0; tt < nt; ++tt) {
    const int b = tt & 3;
    if (tt + 1 < nt) waitvm<4>(); else waitvm<0>();
    bar();  // the only barrier per tile

    const char* Ab = lds + b * 32768 + (wm * 128 + l31) * 64;
    const char* Bb = lds + b * 32768 + 16384 + (wn * 64 + l31) * 64;

    // phase 1: all B frags (2nf x 2ks) + A kstep-0 frags; restage; 8 MFMAs
    i32x8 bf[2][2], af[4];
    #pragma unroll
    for (int nf = 0; nf < 2; ++nf) {
      bf[nf][0] = rd8(Bb + nf * 2048 + pc0);
      bf[nf][1] = rd8(Bb + nf * 2048 + pc1);
    }
    #pragma unroll
    for (int mf = 0; mf < 4; ++mf)
      af[mf] = rd8(Ab + mf * 2048 + pc0);

    if (tt + 2 < nt) stage(tt + 2);

    #pragma unroll
    for (int mf = 0; mf < 4; ++mf)
      #pragma unroll
      for (int nf = 0; nf < 2; ++nf)
        acc[mf][nf] = __builtin_amdgcn_mfma_scale_f32_32x32x64_f8f6f4(
            af[mf], bf[nf][0], acc[mf][nf], 4, 4, 0, SC, 0, SC);

    // phase 2: A kstep-1 frags; 8 MFMAs
    i32x8 ag[4];
    #pragma unroll
    for (int mf = 0; mf < 4; ++mf)
      ag[mf] = rd8(Ab + mf * 2048 + pc1);

    #pragma unroll
    for (int mf = 0; mf < 4; ++mf)
      #pragma unroll
      for (int nf = 0; nf < 2; ++nf)
        acc[mf][nf] = __builtin_amdgcn_mfma_scale_f32_32x32x64_f8f6f4(
            ag[mf], bf[nf][1], acc[mf][nf], 4, 4, 0, SC, 0, SC);
  }

  // --- epilogue: 32x32 C/D layout (m74/m101-verified):
  // col = lane&31, row = (r&3) + 8*(r>>2) + 4*(lane>>5) ---
  const size_t cRow0 = rowA0 + (size_t)wm * 128;
  const size_t cCol0 = rowB0 + (size_t)wn * 64;
  #pragma unroll
  for (int mf = 0; mf < 4; ++mf)
    #pragma unroll
    for (int nf = 0; nf < 2; ++nf)
      #pragma unroll
      for (int r = 0; r < 16; ++r) {
        const int row = (r & 3) + 8 * (r >> 2) + 4 * h;
        C[(cRow0 + mf * 32 + row) * N + cCol0 + nf * 32 + l31] =
            acc[mf][nf][r];
      }
}

// ---------------------------------------------------------------------------
extern "C" void kernel_launch(void* const* d_in, const int* in_sizes, int n_in,
                              void* d_out, int out_size, void* d_ws, size_t ws_size,
                              hipStream_t stream) {
  const float* x = (const float*)d_in[0];
  const float* w = (const float*)d_in[1];
  float* out = (float*)d_out;

  const int K = 4096;
  const int M = in_sizes[0] / K;   // 8192
  const int N = in_sizes[1] / K;   // 4096

  unsigned char* xb = (unsigned char*)d_ws;
  unsigned char* wb = xb + (size_t)M * (K / 2);

  // round-14 binarize: each block = 4096 floats, lane-contiguous
  int bxx = (M * K) / 4096;        // 8192
  int bxw = (N * K) / 4096;        // 4096
  binarize_fp4_v3<<<dim3(bxx + bxw), dim3(256), 0, stream>>>(
      x, w, (unsigned short*)xb, (unsigned short*)wb, bxx);

  int nbm = M / 256;  // 32
  int nbn = N / 256;  // 16
  gemm_bt_fp4<<<dim3(nbm * nbn), dim3(512), 0, stream>>>(
      xb, wb, out, M, N, K, nbn);
}